// Round 7
// baseline (171.181 us; speedup 1.0000x reference)
//
#include <hip/hip_runtime.h>
#include <stdint.h>

// MeshConvPoint: B=8, C=64, V=25000, D=12, O=64
// out[b,o,v] = bias[o] + sum_c W0[o,c]*x[b,c,v] + (1/deg)*sum_{d<deg} y1[b,o,nbr[b,v,d]]
//
// R14: un-serialize the neighbor gathers. Evidence: gather stuck at 46-47us
// across 3 structures (R10 simple / R10 fused / R11-13 persistent). Root
// cause: rows[12] as u32x4 = 48 VGPR of in-flight state vs 36-56 allocated
// -- the compiler CANNOT batch-issue 12 gathers and serializes them into
// ~12 dependent L2 latencies/tile (~12000cy, matches 47us at 2.6 blk/CU).
// gather5: 16 sub-lanes/vertex x u32x2 (8B) chunks -> rows[12]=24 VGPR,
// ns[4], no persistent loop, no prefetch regs (~60 VGPR total). All 12
// gathers issue back-to-back for real. 512 thr / 32 v, one barrier, same
// LDS transpose + full-line out stores. wt/ygemm6 byte-identical (isolation).
// XCD pin everywhere: blockIdx.x&7 = b.

#define NB 8
#define NC 64
#define NV 25000
#define ND 12
#define NO 64
#define VROW 32        // y0/y1 row stride in dwords (64 bf16 = 128 B)
#define NGT 196        // ceil(25000/128) tiles for ygemm6 (128 v / block)
#define GVT 782        // ceil(25000/32)  tiles for gather5 (32 v / block)

typedef uint32_t u32x4 __attribute__((ext_vector_type(4)));
typedef uint32_t u32x2 __attribute__((ext_vector_type(2)));
typedef __bf16  bf16x8 __attribute__((ext_vector_type(8)));
typedef float   f32x4  __attribute__((ext_vector_type(4)));

__device__ inline uint32_t bf16pack(float a, float b) {
    uint32_t ua = __float_as_uint(a), ub = __float_as_uint(b);
    ua = (ua + 0x7fffu + ((ua >> 16) & 1u)) >> 16;
    ub = (ub + 0x7fffu + ((ub >> 16) & 1u)) >> 16;
    return ua | (ub << 16);
}
__device__ inline float blo(uint32_t u) { return __uint_as_float(u << 16); }
__device__ inline float bhi(uint32_t u) { return __uint_as_float(u & 0xffff0000u); }

// ---- K0: W[o][c][k] -> Wcb[m][c-pair] bf16, m = k*64 + o ----
__global__ __launch_bounds__(256) void wt_kernel(const float* __restrict__ W,
                                                 uint32_t* __restrict__ Wcb) {
    int i = blockIdx.x * 256 + threadIdx.x;  // i in [0, 4096)
    int m = i >> 5;             // 0..127
    int c = (i & 31) * 2;       // 0..62 even
    int k = m >> 6;             // plane
    int o = m & 63;
    float s0 = W[o * (NC * 2) + c * 2 + k];
    float s1 = W[o * (NC * 2) + (c + 1) * 2 + k];
    Wcb[i] = bf16pack(s0, s1);
}

// ---- K1: x[b][c][v] -> y0 (plane0+bias) and y1 (plane1), bf16 rows ----
// (byte-identical to R13 for attribution)
__global__ __launch_bounds__(512, 4) void ygemm6(const float* __restrict__ x,
                                                 const uint32_t* __restrict__ Wcb,
                                                 const float* __restrict__ bias,
                                                 uint32_t* __restrict__ y0,
                                                 uint32_t* __restrict__ y1) {
    __shared__ uint32_t lb[4608 + 4096];   // x-tile [128][36] ; +4096 = yst1
    uint32_t* yst0 = lb;                   // aliases x-tile after bar2
    uint32_t* yst1 = lb + 4608;

    const int b = blockIdx.x & 7;      // XCD pin
    const int tile = blockIdx.x >> 3;
    const int vbase = tile * 128;
    const int t = threadIdx.x;
    const int lane = t & 63, wave = t >> 6;
    const float* xb = x + (size_t)b * NC * NV;

    // ---- stage x ----
    {
        int vg = vbase + lane * 2;
        if (vg > NV - 2) vg = NV - 2;      // clamp keeps float2 in bounds
        const int key = ((lane >> 1) & 7) << 2;  // == ((vl>>2)&7)<<2, vl=2*lane(+1)
#pragma unroll
        for (int pp = 0; pp < 4; ++pp) {
            const int p = wave * 4 + pp;   // c-pair 0..31
            const int c = p * 2;
            u32x2 qa = __builtin_nontemporal_load(
                reinterpret_cast<const u32x2*>(xb + (size_t)c * NV + vg));
            u32x2 qb = __builtin_nontemporal_load(
                reinterpret_cast<const u32x2*>(xb + (size_t)(c + 1) * NV + vg));
            const int pc = p ^ key;
            lb[(lane * 2)     * 36 + pc] =
                bf16pack(__uint_as_float(qa[0]), __uint_as_float(qb[0]));
            lb[(lane * 2 + 1) * 36 + pc] =
                bf16pack(__uint_as_float(qa[1]), __uint_as_float(qb[1]));
        }
    }
    __syncthreads();

    // ---- B frags (swizzled read) ----
    const int l15 = lane & 15, lq = lane >> 4;
    const int pl = wave >> 2, sub = wave & 3;

    union BF { u32x4 q; bf16x8 v; } bfr[2][2];   // [sub16][kt]
#pragma unroll
    for (int s = 0; s < 2; ++s) {
        const int vl = sub * 32 + s * 16 + l15;
        const int key = ((vl >> 2) & 7) << 2;
#pragma unroll
        for (int kt = 0; kt < 2; ++kt)
            bfr[s][kt].q = *reinterpret_cast<const u32x4*>(
                &lb[vl * 36 + ((kt * 16 + lq * 4) ^ key)]);
    }
    __syncthreads();   // all frag reads done -> lb reusable as yst0

    f32x4 acc[2][4];
#pragma unroll
    for (int s = 0; s < 2; ++s)
#pragma unroll
        for (int mt = 0; mt < 4; ++mt) acc[s][mt] = (f32x4){0.f, 0.f, 0.f, 0.f};

#pragma unroll
    for (int kt = 0; kt < 2; ++kt) {
#pragma unroll
        for (int mt = 0; mt < 4; ++mt) {
            union { u32x4 q; bf16x8 v; } au;
            au.q = *(const u32x4*)(Wcb + (size_t)(pl * 64 + mt * 16 + l15) * 32
                                       + kt * 16 + lq * 4);
#pragma unroll
            for (int s = 0; s < 2; ++s)
                acc[s][mt] = __builtin_amdgcn_mfma_f32_16x16x32_bf16(au.v, bfr[s][kt].v,
                                                                     acc[s][mt], 0, 0, 0);
        }
    }

    // ---- stage D to LDS (bf16, swizzled; bias on plane 0) ----
    uint32_t* yst = pl ? yst1 : yst0;
#pragma unroll
    for (int s = 0; s < 2; ++s) {
        const int vrow = sub * 32 + s * 16 + l15;
        const int key = (vrow & 7) << 2;
#pragma unroll
        for (int mt = 0; mt < 4; ++mt) {
            f32x4 a = acc[s][mt];
            if (pl == 0) {
                const float* bp = bias + mt * 16 + lq * 4;
                a[0] += bp[0]; a[1] += bp[1]; a[2] += bp[2]; a[3] += bp[3];
            }
            u32x2 pk = {bf16pack(a[0], a[1]), bf16pack(a[2], a[3])};
            *reinterpret_cast<u32x2*>(&yst[vrow * 32 + ((mt * 8 + lq * 2) ^ key)]) = pk;
        }
    }
    __syncthreads();

    // ---- flat full-line copy: per instr 64 lanes x 16 B = 1024 B linear ----
    {
        uint32_t* y0g = y0 + ((size_t)b * NV + vbase) * VROW;
        uint32_t* y1g = y1 + ((size_t)b * NV + vbase) * VROW;
#pragma unroll
        for (int h = 0; h < 2; ++h) {
            const int ck = t + h * 512;        // 4-dw chunk id, 0..1023
            const int r = ck >> 3;             // local row (v)
            if (vbase + r < NV) {
                const int off = ((ck & 7) * 4) ^ ((r & 7) << 2);
                u32x4 q0 = *reinterpret_cast<const u32x4*>(&yst0[r * 32 + off]);
                __builtin_nontemporal_store(q0, reinterpret_cast<u32x4*>(y0g + ck * 4));
                u32x4 q1 = *reinterpret_cast<const u32x4*>(&yst1[r * 32 + off]);
                *reinterpret_cast<u32x4*>(y1g + ck * 4) = q1;   // hot gather target: L2
            }
        }
    }
}

// ---- K2: gather, 16 sub-lanes/vertex, batch-issued 8B row gathers ----
// 512 thr / 32 v per block. Thread (vloc = t>>4, sl = t&15) covers 8 B
// (4 o-channels) of each 128-B y1 row: rows[12] = 24 VGPR in flight ->
// the 12 random gathers issue before any waitcnt. idx/deg loads are
// wave-broadcast (same addr across the 16 sub-lanes). One barrier, then
// the LDS transpose store: per instr 2 o-rows x 32 consecutive v (2x128B).
__global__ __launch_bounds__(512, 4) void gather5(const int* __restrict__ nbr,
                                                  const int* __restrict__ deg,
                                                  const uint32_t* __restrict__ y0,
                                                  const uint32_t* __restrict__ y1,
                                                  float* __restrict__ out) {
    __shared__ float lds[32 * 68];  // [vloc][o], stride 68

    const int b = blockIdx.x & 7;   // XCD pin (matches producer)
    const int tile = blockIdx.x >> 3;
    const int t = threadIdx.x;
    const int vloc = t >> 4;        // 0..31
    const int sl = t & 15;          // sub-lane: dwords sl*2, sl*2+1 of the row
    const int v = tile * 32 + vloc;
    const int vc = v < NV ? v : NV - 1;
    const size_t bv = (size_t)b * NV + vc;

    const uint32_t* y1b = y1 + (size_t)b * NV * VROW;

    // self chunk (read exactly once -> nt), 16 lanes x 8 B = full row
    u32x2 su = __builtin_nontemporal_load(
        reinterpret_cast<const u32x2*>(y0 + bv * VROW) + sl);

    // neighbor indices + degree (same addr across the vertex's 16 lanes)
    int idx[ND];
    {
        const int4* p = reinterpret_cast<const int4*>(nbr + bv * ND);
        int4 a0 = p[0], a1 = p[1], a2 = p[2];
        idx[0] = a0.x; idx[1] = a0.y; idx[2]  = a0.z; idx[3]  = a0.w;
        idx[4] = a1.x; idx[5] = a1.y; idx[6]  = a1.z; idx[7]  = a1.w;
        idx[8] = a2.x; idx[9] = a2.y; idx[10] = a2.z; idx[11] = a2.w;
    }
    const int dg = deg[bv];
    const float inv = 1.0f / (float)dg;

    // batch-issue all masked 8B gathers (24 VGPR in flight -> no serialization)
    u32x2 rows[ND];
#pragma unroll
    for (int d = 0; d < ND; ++d) {
        if (d < dg)
            rows[d] = *(reinterpret_cast<const u32x2*>(
                            y1b + (size_t)idx[d] * VROW) + sl);
    }

    float ns[4];
#pragma unroll
    for (int k = 0; k < 4; ++k) ns[k] = 0.0f;
#pragma unroll
    for (int d = 0; d < ND; ++d) {
        if (d < dg) {
            u32x2 u = rows[d];
            ns[0] += blo(u[0]); ns[1] += bhi(u[0]);
            ns[2] += blo(u[1]); ns[3] += bhi(u[1]);
        }
    }

    // combine with self (y0 already has bias), stage to LDS
    {
        f32x4 w;
        w[0] = __builtin_fmaf(inv, ns[0], blo(su[0]));
        w[1] = __builtin_fmaf(inv, ns[1], bhi(su[0]));
        w[2] = __builtin_fmaf(inv, ns[2], blo(su[1]));
        w[3] = __builtin_fmaf(inv, ns[3], bhi(su[1]));
        *reinterpret_cast<f32x4*>(&lds[vloc * 68 + sl * 4]) = w;
    }
    __syncthreads();

    // coalesced store: per instr 2 o-rows x 32 consecutive v (2x128B lines)
    {
        const int vl = t & 31;
        const int o8 = t >> 5;          // 0..15
        const int vv = tile * 32 + vl;
        if (vv < NV) {
            float* ob = out + (size_t)b * NO * NV + vv;
#pragma unroll
            for (int oo = 0; oo < 4; ++oo) {
                const int o = oo * 16 + o8;
                __builtin_nontemporal_store(lds[vl * 68 + o], ob + (size_t)o * NV);
            }
        }
    }
}

// ---- Fallback (workspace too small): correct but slow ----
__global__ __launch_bounds__(64) void fallback_kernel(const float* __restrict__ x,
                                                      const int* __restrict__ nbr,
                                                      const int* __restrict__ deg,
                                                      const float* __restrict__ W,
                                                      const float* __restrict__ bias,
                                                      float* __restrict__ out) {
    const int bvi = blockIdx.x;
    const int b = bvi / NV, v = bvi % NV;
    const int o = threadIdx.x;
    const int degv = deg[bvi];
    const float inv = 1.0f / (float)degv;
    float acc = bias[o];
    for (int c = 0; c < NC; ++c) {
        const float* xc = x + ((size_t)b * NC + c) * NV;
        float m = 0.0f;
        for (int d = 0; d < degv; ++d) m += xc[nbr[(size_t)bvi * ND + d]];
        acc += W[o * (NC * 2) + c * 2] * xc[v] + W[o * (NC * 2) + c * 2 + 1] * (m * inv);
    }
    out[((size_t)b * NO + o) * NV + v] = acc;
}

extern "C" void kernel_launch(void* const* d_in, const int* in_sizes, int n_in,
                              void* d_out, int out_size, void* d_ws, size_t ws_size,
                              hipStream_t stream) {
    const float* x    = (const float*)d_in[0];
    const int*   nbr  = (const int*)d_in[1];
    const int*   deg  = (const int*)d_in[2];
    const float* W    = (const float*)d_in[3];
    const float* bias = (const float*)d_in[4];
    float* out = (float*)d_out;

    const size_t wcb_dw = 4096;                     // 128x64 bf16 as dwords
    const size_t plane  = (size_t)NB * NV * VROW;   // dwords per bf16 plane
    const size_t need = (wcb_dw + 2 * plane) * 4;   // Wcb + y0 + y1
    if (ws_size >= need) {
        uint32_t* Wcb = (uint32_t*)d_ws;
        uint32_t* y0  = Wcb + wcb_dw;
        uint32_t* y1  = y0 + plane;
        wt_kernel<<<dim3(16), 256, 0, stream>>>(W, Wcb);
        ygemm6<<<dim3(NB * NGT), 512, 0, stream>>>(x, Wcb, bias, y0, y1);
        gather5<<<dim3(NB * GVT), 512, 0, stream>>>(nbr, deg, y0, y1, out);
    } else {
        fallback_kernel<<<dim3(NB * NV), 64, 0, stream>>>(x, nbr, deg, W, bias, out);
    }
}